// Round 27
// baseline (70.574 us; speedup 1.0000x reference)
//
#include <hip/hip_runtime.h>
#include <math.h>

#define EE 256
#define HH 8
#define DD 32
#define NB 8
#define NS 1024
#define SLOPE 0.2f

typedef float f32x4 __attribute__((ext_vector_type(4)));
typedef short short8 __attribute__((ext_vector_type(8)));

static __device__ __forceinline__ unsigned short f2b(float f) {
    unsigned int u = __float_as_uint(f);
    u = (u + 0x7FFFu + ((u >> 16) & 1u)) >> 16;   // RNE; inputs finite
    return (unsigned short)u;
}

static __device__ __forceinline__ unsigned int cvtpk(float lo, float hi) {
    unsigned int r;
    asm("v_cvt_pk_bf16_f32 %0, %1, %2" : "=v"(r) : "v"(lo), "v"(hi));
    return r;
}

static __device__ __forceinline__ void gload_lds16(const void* g, void* l) {
    __builtin_amdgcn_global_load_lds(
        (const __attribute__((address_space(1))) unsigned int*)g,
        (__attribute__((address_space(3))) unsigned int*)l, 16, 0, 0);
}

// ---------- fused prep: [0,560) cvt x+w_in (16 elems/thread); [560,688) adj bitmask;
// ---------- [688,944) W_comb = w_lin @ w_out, b_comb = w_lin@b_out + b_lin ----------
__global__ __launch_bounds__(256) void prep(
    const float* __restrict__ x, const float* __restrict__ wi,
    const float* __restrict__ wo, const float* __restrict__ bo,
    const float* __restrict__ wl, const float* __restrict__ bl,
    const int* __restrict__ adj,
    unsigned short* __restrict__ xb, unsigned short* __restrict__ wib,
    unsigned short* __restrict__ wcb, float* __restrict__ bcomb,
    unsigned int* __restrict__ bits) {
    int blk = blockIdx.x;
    if (blk < 560) {
        int t = blk * 256 + threadIdx.x;          // 143360 units of 16
        const float* src; unsigned short* dst; int base;
        if (t < 131072) { src = x;  dst = xb;  base = t; }
        else            { src = wi; dst = wib; base = t - 131072; }
        const float4* s = (const float4*)(src + (size_t)base * 16);
        float4 a = s[0], b = s[1], cc4 = s[2], d4 = s[3];
        uint4 w0, w1;
        w0.x = cvtpk(a.x, a.y);  w0.y = cvtpk(a.z, a.w);
        w0.z = cvtpk(b.x, b.y);  w0.w = cvtpk(b.z, b.w);
        w1.x = cvtpk(cc4.x, cc4.y); w1.y = cvtpk(cc4.z, cc4.w);
        w1.z = cvtpk(d4.x, d4.y);   w1.w = cvtpk(d4.z, d4.w);
        uint4* dp = (uint4*)(dst + (size_t)base * 16);
        dp[0] = w0;
        dp[1] = w1;
    } else if (blk < 688) {
        int t = (blk - 560) * 256 + threadIdx.x;  // word index 0..32767
        int n = t >> 5, w = t & 31;
        const int* p = adj + (size_t)n * NS + w * 32;
        unsigned int word = 0;
#pragma unroll
        for (int i = 0; i < 32; i += 4) {
            int4 a = *(const int4*)(p + i);
            if (a.x) word |= 1u << i;
            if (a.y) word |= 1u << (i + 1);
            if (a.z) word |= 1u << (i + 2);
            if (a.w) word |= 1u << (i + 3);
        }
        bits[t] = word;
    } else {
        int o = blk - 688, c = threadIdx.x;
        const float* wlr = wl + (size_t)o * EE;
        float acc = 0.f;
#pragma unroll 8
        for (int e = 0; e < EE; ++e)
            acc = fmaf(wlr[e], wo[(size_t)e * EE + c], acc);
        wcb[(size_t)o * EE + c] = f2b(acc);
        if (c == 0) {
            float bb = bl[o];
            for (int e = 0; e < EE; ++e) bb = fmaf(wlr[e], bo[e], bb);
            bcomb[o] = bb;
        }
    }
}

// ---------- MFMA GEMM: C[M][Nout] = A[M][256] @ W[Nout][256]^T + bias ----------
// BM x 64 tile, BK=64, 4 waves (2x2), wave tile (BM/2)x32, global_load_lds staging.
// MODE 1: fp32 out + leaky (BM=64, grid 512 = 2/CU, XCD-swizzled).
// MODE 2: qkv scatter (BM=128, grid 768 = 3/CU, XCD-swizzled; q scaled, vT permuted:
//         pos = ((n&12)<<1)|((n&16)>>2)|(n&3) within each 32-key chunk).
template<int MODE, int BM>
__global__ __launch_bounds__(256) void gemm_mfma(
    const unsigned short* __restrict__ A, const unsigned short* __restrict__ W,
    const float* __restrict__ bias, void* __restrict__ out,
    unsigned short* __restrict__ qb, unsigned short* __restrict__ kb,
    unsigned short* __restrict__ vtb, int Nout) {
    const int MI = BM / 32;                       // M-frags per wave
    __shared__ __align__(16) unsigned short As[BM * 64];
    __shared__ __align__(16) unsigned short Bs[64 * 64];
    int tid = threadIdx.x, w = tid >> 6, lane = tid & 63;
    int lq = lane & 15, g = lane >> 4;
    int wr = w >> 1, wc = w & 1;
    int f = blockIdx.x;
    int m0, n0;
    if (MODE == 2) {        // 768 blocks: 8 XCD groups x (8 my x 12 nx)
        int xcd = f & 7, i = f >> 3;
        m0 = (xcd * 8 + i / 12) * 128;
        n0 = (i % 12) * 64;
    } else {                // 512 blocks: 8 XCD groups x (16 my x 4 nx), BM=64
        int xcd = f & 7, i = f >> 3;
        m0 = (xcd * 16 + (i >> 2)) * 64;
        n0 = (i & 3) * 64;
    }
    int r8 = lane >> 3, c8 = (lane & 7) * 8;
    f32x4 acc[MI][2];
#pragma unroll
    for (int i = 0; i < MI; ++i)
#pragma unroll
        for (int j = 0; j < 2; ++j) acc[i][j] = (f32x4){0.f, 0.f, 0.f, 0.f};

    for (int k0 = 0; k0 < 256; k0 += 64) {
        __syncthreads();
#pragma unroll
        for (int i = 0; i < MI; ++i)
            gload_lds16(A + (size_t)(m0 + w * (BM / 4) + i * 8 + r8) * 256 + k0 + c8,
                        &As[(w * (BM / 4) + i * 8) * 64]);
#pragma unroll
        for (int i = 0; i < 2; ++i)
            gload_lds16(W + (size_t)(n0 + w * 16 + i * 8 + r8) * 256 + k0 + c8,
                        &Bs[(w * 16 + i * 8) * 64]);
        __syncthreads();   // drains lgkm + vmcnt (global_load_lds)
#pragma unroll
        for (int ks = 0; ks < 2; ++ks) {
            short8 af[MI], bf[2];
#pragma unroll
            for (int mi = 0; mi < MI; ++mi)
                af[mi] = *(const short8*)(&As[(wr * (BM / 2) + mi * 16 + lq) * 64 + ks * 32 + g * 8]);
#pragma unroll
            for (int ni = 0; ni < 2; ++ni)
                bf[ni] = *(const short8*)(&Bs[(wc * 32 + ni * 16 + lq) * 64 + ks * 32 + g * 8]);
#pragma unroll
            for (int mi = 0; mi < MI; ++mi)
#pragma unroll
                for (int ni = 0; ni < 2; ++ni)
                    acc[mi][ni] = __builtin_amdgcn_mfma_f32_16x16x32_bf16(af[mi], bf[ni], acc[mi][ni], 0, 0, 0);
        }
    }
    const float scale = 0.17677669529663687f;
#pragma unroll
    for (int mi = 0; mi < MI; ++mi) {
#pragma unroll
        for (int reg = 0; reg < 4; ++reg) {
            int m = m0 + wr * (BM / 2) + mi * 16 + g * 4 + reg;
#pragma unroll
            for (int ni = 0; ni < 2; ++ni) {
                int n = n0 + wc * 32 + ni * 16 + lq;
                float v = acc[mi][ni][reg] + bias[n];
                if (MODE == 1) {
                    v = v >= 0.f ? v : SLOPE * v;
                    ((float*)out)[(size_t)m * Nout + n] = v;
                } else {
                    int sec = n >> 8, cc = n & 255, h = cc >> 5, d = cc & 31;
                    int b = m >> 10, nr = m & (NS - 1);
                    if (sec == 0)
                        qb[((size_t)(b * HH + h) * NS + nr) * DD + d] = f2b(v * scale);
                    else if (sec == 1)
                        kb[((size_t)(b * HH + h) * NS + nr) * DD + d] = f2b(v);
                    else {
                        int nrp = (nr & ~31) | ((nr & 12) << 1) | ((nr & 16) >> 2) | (nr & 3);
                        vtb[((size_t)(b * HH + h) * DD + d) * NS + nrp] = f2b(v);
                    }
                }
            }
        }
    }
}

// ---------- MFMA flash attention: no-max softmax, register P, KV=128 ----------
// BISECTION: K read DIRECT from global (value-identical addresses, wave-coalesced,
// L2-hot via XCD swizzle); V kept in double-buffered LDS exactly as passing R20/R26.
// Barriers, buffer toggle, setprio, epilogue unchanged from the verified kernel.
__global__ __launch_bounds__(256) void attn_mfma(
    const unsigned short* __restrict__ q, const unsigned short* __restrict__ k,
    const unsigned short* __restrict__ vt, const unsigned int* __restrict__ adjbits,
    unsigned short* __restrict__ ctx) {
    __shared__ __align__(16) unsigned short Vs[2][32 * 136];   // [d][perm key] pad 128->136
    int tid = threadIdx.x;
    int w = tid >> 6, lane = tid & 63;
    int lq = lane & 15, g = lane >> 4;
    int f = blockIdx.x;
    int xcd = f & 7, i = f >> 3;       // i < 128
    int bh = xcd * 8 + (i >> 4);       // 8 bh per XCD
    int n0 = (i & 15) * 64;
    int nq = n0 + w * 16 + lq;
    const unsigned short* qb = q + (size_t)bh * NS * DD;
    const unsigned short* kbp = k + (size_t)bh * NS * DD;
    const unsigned short* vbp = vt + (size_t)bh * DD * NS;
    short8 qfrag = *(const short8*)(qb + (size_t)nq * DD + g * 8);
    const unsigned int* abr = adjbits + (size_t)nq * 32;
    float lsA = 0.f, lsB = 0.f;
    f32x4 acc0 = {0.f, 0.f, 0.f, 0.f}, acc1 = {0.f, 0.f, 0.f, 0.f};
    int vd = tid >> 3, vc = (tid & 7) * 16;    // V: 32 d x 128 keys (pre-permuted)
    const unsigned short* vst = vbp + (size_t)vd * NS + vc;   // + t*128

    // prologue: V tile 0
    int4 va = *(const int4*)(vst);
    int4 vb2 = *(const int4*)(vst + 8);
    *(int4*)(&Vs[0][vd * 136 + vc])     = va;
    *(int4*)(&Vs[0][vd * 136 + vc + 8]) = vb2;
    __syncthreads();

    int c = 0;
    for (int t = 0; t < 8; ++t) {
        if (t < 7) {   // issue next V tile's loads early (latency hides under compute)
            const unsigned short* vn = vst + (size_t)(t + 1) * 128;
            va  = *(const int4*)(vn);
            vb2 = *(const int4*)(vn + 8);
        }
        int m0 = t * 128;
        const unsigned short* vsl = Vs[c];
        uint4 w4 = *(const uint4*)(abr + t * 4);
        const f32x4 z = {0.f, 0.f, 0.f, 0.f};
        __builtin_amdgcn_s_setprio(1);
#pragma unroll
        for (int T = 0; T < 4; ++T) {   // 32-key chunk
            unsigned int wdT = (T == 0) ? w4.x : (T == 1) ? w4.y : (T == 2) ? w4.z : w4.w;
            const unsigned short* krow = kbp + (size_t)(m0 + 32 * T + lq) * DD + g * 8;
            short8 kf0 = *(const short8*)(krow);               // key m0+32T+lq
            short8 kf1 = *(const short8*)(krow + 16 * DD);     // key m0+32T+16+lq
            f32x4 s0 = __builtin_amdgcn_mfma_f32_16x16x32_bf16(kf0, qfrag, z, 0, 0, 0);
            f32x4 s1 = __builtin_amdgcn_mfma_f32_16x16x32_bf16(kf1, qfrag, z, 0, 0, 0);
            unsigned int b0 = wdT >> (4 * g);         // keys m0+32T+4g+r
            unsigned int b1 = wdT >> (16 + 4 * g);    // keys m0+32T+16+4g+r
            float p0 = ((b0 >> 0) & 1u) ? __expf(s0[0]) : 0.f;
            float p1 = ((b0 >> 1) & 1u) ? __expf(s0[1]) : 0.f;
            float p2 = ((b0 >> 2) & 1u) ? __expf(s0[2]) : 0.f;
            float p3 = ((b0 >> 3) & 1u) ? __expf(s0[3]) : 0.f;
            float p4 = ((b1 >> 0) & 1u) ? __expf(s1[0]) : 0.f;
            float p5 = ((b1 >> 1) & 1u) ? __expf(s1[1]) : 0.f;
            float p6 = ((b1 >> 2) & 1u) ? __expf(s1[2]) : 0.f;
            float p7 = ((b1 >> 3) & 1u) ? __expf(s1[3]) : 0.f;
            lsA += (p0 + p1) + (p2 + p3);
            lsB += (p4 + p5) + (p6 + p7);
            union { uint4 u; short8 s; } pb;
            pb.u.x = cvtpk(p0, p1); pb.u.y = cvtpk(p2, p3);
            pb.u.z = cvtpk(p4, p5); pb.u.w = cvtpk(p6, p7);
            short8 va0 = *(const short8*)(&vsl[lq * 136 + T * 32 + g * 8]);
            short8 va1 = *(const short8*)(&vsl[(16 + lq) * 136 + T * 32 + g * 8]);
            acc0 = __builtin_amdgcn_mfma_f32_16x16x32_bf16(va0, pb.s, acc0, 0, 0, 0);
            acc1 = __builtin_amdgcn_mfma_f32_16x16x32_bf16(va1, pb.s, acc1, 0, 0, 0);
        }
        __builtin_amdgcn_s_setprio(0);
        if (t < 7) {   // write next V tile into the other buffer
            *(int4*)(&Vs[c ^ 1][vd * 136 + vc])     = va;
            *(int4*)(&Vs[c ^ 1][vd * 136 + vc + 8]) = vb2;
        }
        __syncthreads();
        c ^= 1;
    }
    float rs = lsA + lsB;
    rs += __shfl_xor(rs, 16);
    rs += __shfl_xor(rs, 32);
    float inv = 1.f / rs;
    int b = bh >> 3, h = bh & 7;
    unsigned short* dst = ctx + ((size_t)(b * NS + nq)) * EE + h * DD;
    uint2 o0, o1;
    o0.x = cvtpk(acc0[0] * inv, acc0[1] * inv);
    o0.y = cvtpk(acc0[2] * inv, acc0[3] * inv);
    o1.x = cvtpk(acc1[0] * inv, acc1[1] * inv);
    o1.y = cvtpk(acc1[2] * inv, acc1[3] * inv);
    *(uint2*)(dst + 4 * g) = o0;        // d = 4g..4g+3
    *(uint2*)(dst + 16 + 4 * g) = o1;   // d = 16+4g..16+4g+3
}

extern "C" void kernel_launch(void* const* d_in, const int* in_sizes, int n_in,
                              void* d_out, int out_size, void* d_ws, size_t ws_size,
                              hipStream_t stream) {
    const float* x     = (const float*)d_in[0];
    const int*   adj   = (const int*)d_in[1];
    const float* w_in  = (const float*)d_in[2];
    const float* b_in  = (const float*)d_in[3];
    const float* w_out = (const float*)d_in[4];
    const float* b_out = (const float*)d_in[5];
    const float* w_lin = (const float*)d_in[6];
    const float* b_lin = (const float*)d_in[7];
    float* out = (float*)d_out;

    const size_t S = (size_t)NB * HH * NS * DD;   // 2M elements
    unsigned short* qb   = (unsigned short*)d_ws;
    unsigned short* kb   = qb + S;
    unsigned short* vtb  = kb + S;
    unsigned short* ctxb = vtb + S;
    unsigned short* xb   = ctxb + S;
    unsigned short* wib  = xb + S;                // 768*256
    unsigned short* wcb  = wib + 768 * 256;       // 256*256
    unsigned int* adjbits = (unsigned int*)(wcb + 256 * 256);  // 32768 words
    float* bcomb = (float*)(adjbits + 32768);     // 256 floats

    dim3 blk(256);
    prep<<<dim3(944), blk, 0, stream>>>(x, w_in, w_out, b_out, w_lin, b_lin, adj,
                                        xb, wib, wcb, bcomb, adjbits);
    gemm_mfma<2, 128><<<dim3(768), blk, 0, stream>>>(xb, wib, b_in, nullptr, qb, kb, vtb, 768);
    attn_mfma<<<dim3(1024), blk, 0, stream>>>(qb, kb, vtb, adjbits, ctxb);
    gemm_mfma<1, 64><<<dim3(512), blk, 0, stream>>>(ctxb, wcb, bcomb, out, nullptr, nullptr, nullptr, 256);
}

// Round 28
// 66.733 us; speedup vs baseline: 1.0576x; 1.0576x over previous
//
#include <hip/hip_runtime.h>
#include <math.h>

#define EE 256
#define HH 8
#define DD 32
#define NB 8
#define NS 1024
#define SLOPE 0.2f

typedef float f32x4 __attribute__((ext_vector_type(4)));
typedef short short8 __attribute__((ext_vector_type(8)));

static __device__ __forceinline__ unsigned short f2b(float f) {
    unsigned int u = __float_as_uint(f);
    u = (u + 0x7FFFu + ((u >> 16) & 1u)) >> 16;   // RNE; inputs finite
    return (unsigned short)u;
}

static __device__ __forceinline__ unsigned int cvtpk(float lo, float hi) {
    unsigned int r;
    asm("v_cvt_pk_bf16_f32 %0, %1, %2" : "=v"(r) : "v"(lo), "v"(hi));
    return r;
}

static __device__ __forceinline__ void gload_lds16(const void* g, void* l) {
    __builtin_amdgcn_global_load_lds(
        (const __attribute__((address_space(1))) unsigned int*)g,
        (__attribute__((address_space(3))) unsigned int*)l, 16, 0, 0);
}

// ---------- fused prep: [0,560) cvt x+w_in (16 elems/thread); [560,688) adj bitmask;
// ---------- [688,944) W_comb = w_lin @ w_out, b_comb = w_lin@b_out + b_lin ----------
__global__ __launch_bounds__(256) void prep(
    const float* __restrict__ x, const float* __restrict__ wi,
    const float* __restrict__ wo, const float* __restrict__ bo,
    const float* __restrict__ wl, const float* __restrict__ bl,
    const int* __restrict__ adj,
    unsigned short* __restrict__ xb, unsigned short* __restrict__ wib,
    unsigned short* __restrict__ wcb, float* __restrict__ bcomb,
    unsigned int* __restrict__ bits) {
    int blk = blockIdx.x;
    if (blk < 560) {
        int t = blk * 256 + threadIdx.x;          // 143360 units of 16
        const float* src; unsigned short* dst; int base;
        if (t < 131072) { src = x;  dst = xb;  base = t; }
        else            { src = wi; dst = wib; base = t - 131072; }
        const float4* s = (const float4*)(src + (size_t)base * 16);
        float4 a = s[0], b = s[1], cc4 = s[2], d4 = s[3];
        uint4 w0, w1;
        w0.x = cvtpk(a.x, a.y);  w0.y = cvtpk(a.z, a.w);
        w0.z = cvtpk(b.x, b.y);  w0.w = cvtpk(b.z, b.w);
        w1.x = cvtpk(cc4.x, cc4.y); w1.y = cvtpk(cc4.z, cc4.w);
        w1.z = cvtpk(d4.x, d4.y);   w1.w = cvtpk(d4.z, d4.w);
        uint4* dp = (uint4*)(dst + (size_t)base * 16);
        dp[0] = w0;
        dp[1] = w1;
    } else if (blk < 688) {
        int t = (blk - 560) * 256 + threadIdx.x;  // word index 0..32767
        int n = t >> 5, w = t & 31;
        const int* p = adj + (size_t)n * NS + w * 32;
        unsigned int word = 0;
#pragma unroll
        for (int i = 0; i < 32; i += 4) {
            int4 a = *(const int4*)(p + i);
            if (a.x) word |= 1u << i;
            if (a.y) word |= 1u << (i + 1);
            if (a.z) word |= 1u << (i + 2);
            if (a.w) word |= 1u << (i + 3);
        }
        bits[t] = word;
    } else {
        int o = blk - 688, c = threadIdx.x;
        const float* wlr = wl + (size_t)o * EE;
        float acc = 0.f;
#pragma unroll 8
        for (int e = 0; e < EE; ++e)
            acc = fmaf(wlr[e], wo[(size_t)e * EE + c], acc);
        wcb[(size_t)o * EE + c] = f2b(acc);
        if (c == 0) {
            float bb = bl[o];
            for (int e = 0; e < EE; ++e) bb = fmaf(wlr[e], bo[e], bb);
            bcomb[o] = bb;
        }
    }
}

// ---------- MFMA GEMM: C[M][Nout] = A[M][256] @ W[Nout][256]^T + bias ----------
// BM x 64 tile, BK=64, 4 waves (2x2), wave tile (BM/2)x32, global_load_lds staging.
// MODE 1: fp32 out + leaky (BM=64, grid 512 = 2/CU, XCD-swizzled).
// MODE 2: qkv scatter (BM=128, grid 768 = 3/CU, XCD-swizzled; q scaled, vT permuted:
//         pos = ((n&12)<<1)|((n&16)>>2)|(n&3) within each 32-key chunk).
template<int MODE, int BM>
__global__ __launch_bounds__(256) void gemm_mfma(
    const unsigned short* __restrict__ A, const unsigned short* __restrict__ W,
    const float* __restrict__ bias, void* __restrict__ out,
    unsigned short* __restrict__ qb, unsigned short* __restrict__ kb,
    unsigned short* __restrict__ vtb, int Nout) {
    const int MI = BM / 32;                       // M-frags per wave
    __shared__ __align__(16) unsigned short As[BM * 64];
    __shared__ __align__(16) unsigned short Bs[64 * 64];
    int tid = threadIdx.x, w = tid >> 6, lane = tid & 63;
    int lq = lane & 15, g = lane >> 4;
    int wr = w >> 1, wc = w & 1;
    int f = blockIdx.x;
    int m0, n0;
    if (MODE == 2) {        // 768 blocks: 8 XCD groups x (8 my x 12 nx)
        int xcd = f & 7, i = f >> 3;
        m0 = (xcd * 8 + i / 12) * 128;
        n0 = (i % 12) * 64;
    } else {                // 512 blocks: 8 XCD groups x (16 my x 4 nx), BM=64
        int xcd = f & 7, i = f >> 3;
        m0 = (xcd * 16 + (i >> 2)) * 64;
        n0 = (i & 3) * 64;
    }
    int r8 = lane >> 3, c8 = (lane & 7) * 8;
    f32x4 acc[MI][2];
#pragma unroll
    for (int i = 0; i < MI; ++i)
#pragma unroll
        for (int j = 0; j < 2; ++j) acc[i][j] = (f32x4){0.f, 0.f, 0.f, 0.f};

    for (int k0 = 0; k0 < 256; k0 += 64) {
        __syncthreads();
#pragma unroll
        for (int i = 0; i < MI; ++i)
            gload_lds16(A + (size_t)(m0 + w * (BM / 4) + i * 8 + r8) * 256 + k0 + c8,
                        &As[(w * (BM / 4) + i * 8) * 64]);
#pragma unroll
        for (int i = 0; i < 2; ++i)
            gload_lds16(W + (size_t)(n0 + w * 16 + i * 8 + r8) * 256 + k0 + c8,
                        &Bs[(w * 16 + i * 8) * 64]);
        __syncthreads();   // drains lgkm + vmcnt (global_load_lds)
#pragma unroll
        for (int ks = 0; ks < 2; ++ks) {
            short8 af[MI], bf[2];
#pragma unroll
            for (int mi = 0; mi < MI; ++mi)
                af[mi] = *(const short8*)(&As[(wr * (BM / 2) + mi * 16 + lq) * 64 + ks * 32 + g * 8]);
#pragma unroll
            for (int ni = 0; ni < 2; ++ni)
                bf[ni] = *(const short8*)(&Bs[(wc * 32 + ni * 16 + lq) * 64 + ks * 32 + g * 8]);
#pragma unroll
            for (int mi = 0; mi < MI; ++mi)
#pragma unroll
                for (int ni = 0; ni < 2; ++ni)
                    acc[mi][ni] = __builtin_amdgcn_mfma_f32_16x16x32_bf16(af[mi], bf[ni], acc[mi][ni], 0, 0, 0);
        }
    }
    const float scale = 0.17677669529663687f;
#pragma unroll
    for (int mi = 0; mi < MI; ++mi) {
#pragma unroll
        for (int reg = 0; reg < 4; ++reg) {
            int m = m0 + wr * (BM / 2) + mi * 16 + g * 4 + reg;
#pragma unroll
            for (int ni = 0; ni < 2; ++ni) {
                int n = n0 + wc * 32 + ni * 16 + lq;
                float v = acc[mi][ni][reg] + bias[n];
                if (MODE == 1) {
                    v = v >= 0.f ? v : SLOPE * v;
                    ((float*)out)[(size_t)m * Nout + n] = v;
                } else {
                    int sec = n >> 8, cc = n & 255, h = cc >> 5, d = cc & 31;
                    int b = m >> 10, nr = m & (NS - 1);
                    if (sec == 0)
                        qb[((size_t)(b * HH + h) * NS + nr) * DD + d] = f2b(v * scale);
                    else if (sec == 1)
                        kb[((size_t)(b * HH + h) * NS + nr) * DD + d] = f2b(v);
                    else {
                        int nrp = (nr & ~31) | ((nr & 12) << 1) | ((nr & 16) >> 2) | (nr & 3);
                        vtb[((size_t)(b * HH + h) * DD + d) * NS + nrp] = f2b(v);
                    }
                }
            }
        }
    }
}

// ---------- MFMA flash attention: no-max softmax, KV=128, register P, ----------
// double-buffered LDS, async-stage split. 1D grid 1024, XCD-swizzled:
// all 16 chunk-blocks of one bh land on the same XCD (K/V L2-resident).
__global__ __launch_bounds__(256) void attn_mfma(
    const unsigned short* __restrict__ q, const unsigned short* __restrict__ k,
    const unsigned short* __restrict__ vt, const unsigned int* __restrict__ adjbits,
    unsigned short* __restrict__ ctx) {
    __shared__ __align__(16) unsigned short Ks[2][128 * 40];   // [key][d] pad 32->40
    __shared__ __align__(16) unsigned short Vs[2][32 * 136];   // [d][perm key] pad 128->136
    int tid = threadIdx.x;
    int w = tid >> 6, lane = tid & 63;
    int lq = lane & 15, g = lane >> 4;
    int f = blockIdx.x;
    int xcd = f & 7, i = f >> 3;       // i < 128
    int bh = xcd * 8 + (i >> 4);       // 8 bh per XCD
    int n0 = (i & 15) * 64;
    int nq = n0 + w * 16 + lq;
    const unsigned short* qb = q + (size_t)bh * NS * DD;
    const unsigned short* kbp = k + (size_t)bh * NS * DD;
    const unsigned short* vbp = vt + (size_t)bh * DD * NS;
    short8 qfrag = *(const short8*)(qb + (size_t)nq * DD + g * 8);
    const unsigned int* abr = adjbits + (size_t)nq * 32;
    float lsA = 0.f, lsB = 0.f;
    f32x4 acc0 = {0.f, 0.f, 0.f, 0.f}, acc1 = {0.f, 0.f, 0.f, 0.f};
    int kr = tid >> 1, kc = (tid & 1) * 16;    // K: 128 rows x 32 d
    int vd = tid >> 3, vc = (tid & 7) * 16;    // V: 32 d x 128 keys (pre-permuted)
    const unsigned short* kst = kbp + (size_t)kr * DD + kc;   // + t*128*DD
    const unsigned short* vst = vbp + (size_t)vd * NS + vc;   // + t*128

    // prologue: tile 0
    int4 ka = *(const int4*)(kst);
    int4 kb2 = *(const int4*)(kst + 8);
    int4 va = *(const int4*)(vst);
    int4 vb2 = *(const int4*)(vst + 8);
    *(int4*)(&Ks[0][kr * 40 + kc])     = ka;
    *(int4*)(&Ks[0][kr * 40 + kc + 8]) = kb2;
    *(int4*)(&Vs[0][vd * 136 + vc])     = va;
    *(int4*)(&Vs[0][vd * 136 + vc + 8]) = vb2;
    __syncthreads();

    int c = 0;
    for (int t = 0; t < 8; ++t) {
        if (t < 7) {   // issue next tile's loads early (latency hides under compute)
            const unsigned short* kn = kst + (size_t)(t + 1) * 128 * DD;
            const unsigned short* vn = vst + (size_t)(t + 1) * 128;
            ka  = *(const int4*)(kn);
            kb2 = *(const int4*)(kn + 8);
            va  = *(const int4*)(vn);
            vb2 = *(const int4*)(vn + 8);
        }
        const unsigned short* ksl = Ks[c];
        const unsigned short* vsl = Vs[c];
        uint4 w4 = *(const uint4*)(abr + t * 4);
        const f32x4 z = {0.f, 0.f, 0.f, 0.f};
        __builtin_amdgcn_s_setprio(1);
#pragma unroll
        for (int T = 0; T < 4; ++T) {   // 32-key chunk
            unsigned int wdT = (T == 0) ? w4.x : (T == 1) ? w4.y : (T == 2) ? w4.z : w4.w;
            short8 kf0 = *(const short8*)(&ksl[(32 * T + lq) * 40 + g * 8]);
            short8 kf1 = *(const short8*)(&ksl[(32 * T + 16 + lq) * 40 + g * 8]);
            f32x4 s0 = __builtin_amdgcn_mfma_f32_16x16x32_bf16(kf0, qfrag, z, 0, 0, 0);
            f32x4 s1 = __builtin_amdgcn_mfma_f32_16x16x32_bf16(kf1, qfrag, z, 0, 0, 0);
            unsigned int b0 = wdT >> (4 * g);         // keys 32T+4g+r
            unsigned int b1 = wdT >> (16 + 4 * g);    // keys 32T+16+4g+r
            float p0 = ((b0 >> 0) & 1u) ? __expf(s0[0]) : 0.f;
            float p1 = ((b0 >> 1) & 1u) ? __expf(s0[1]) : 0.f;
            float p2 = ((b0 >> 2) & 1u) ? __expf(s0[2]) : 0.f;
            float p3 = ((b0 >> 3) & 1u) ? __expf(s0[3]) : 0.f;
            float p4 = ((b1 >> 0) & 1u) ? __expf(s1[0]) : 0.f;
            float p5 = ((b1 >> 1) & 1u) ? __expf(s1[1]) : 0.f;
            float p6 = ((b1 >> 2) & 1u) ? __expf(s1[2]) : 0.f;
            float p7 = ((b1 >> 3) & 1u) ? __expf(s1[3]) : 0.f;
            lsA += (p0 + p1) + (p2 + p3);
            lsB += (p4 + p5) + (p6 + p7);
            union { uint4 u; short8 s; } pb;
            pb.u.x = cvtpk(p0, p1); pb.u.y = cvtpk(p2, p3);
            pb.u.z = cvtpk(p4, p5); pb.u.w = cvtpk(p6, p7);
            short8 va0 = *(const short8*)(&vsl[lq * 136 + T * 32 + g * 8]);
            short8 va1 = *(const short8*)(&vsl[(16 + lq) * 136 + T * 32 + g * 8]);
            acc0 = __builtin_amdgcn_mfma_f32_16x16x32_bf16(va0, pb.s, acc0, 0, 0, 0);
            acc1 = __builtin_amdgcn_mfma_f32_16x16x32_bf16(va1, pb.s, acc1, 0, 0, 0);
        }
        __builtin_amdgcn_s_setprio(0);
        if (t < 7) {   // write next tile into the other buffer (old readers done at t-1's barrier)
            *(int4*)(&Ks[c ^ 1][kr * 40 + kc])     = ka;
            *(int4*)(&Ks[c ^ 1][kr * 40 + kc + 8]) = kb2;
            *(int4*)(&Vs[c ^ 1][vd * 136 + vc])     = va;
            *(int4*)(&Vs[c ^ 1][vd * 136 + vc + 8]) = vb2;
        }
        __syncthreads();
        c ^= 1;
    }
    float rs = lsA + lsB;
    rs += __shfl_xor(rs, 16);
    rs += __shfl_xor(rs, 32);
    float inv = 1.f / rs;
    int b = bh >> 3, h = bh & 7;
    unsigned short* dst = ctx + ((size_t)(b * NS + nq)) * EE + h * DD;
    uint2 o0, o1;
    o0.x = cvtpk(acc0[0] * inv, acc0[1] * inv);
    o0.y = cvtpk(acc0[2] * inv, acc0[3] * inv);
    o1.x = cvtpk(acc1[0] * inv, acc1[1] * inv);
    o1.y = cvtpk(acc1[2] * inv, acc1[3] * inv);
    *(uint2*)(dst + 4 * g) = o0;        // d = 4g..4g+3
    *(uint2*)(dst + 16 + 4 * g) = o1;   // d = 16+4g..16+4g+3
}

extern "C" void kernel_launch(void* const* d_in, const int* in_sizes, int n_in,
                              void* d_out, int out_size, void* d_ws, size_t ws_size,
                              hipStream_t stream) {
    const float* x     = (const float*)d_in[0];
    const int*   adj   = (const int*)d_in[1];
    const float* w_in  = (const float*)d_in[2];
    const float* b_in  = (const float*)d_in[3];
    const float* w_out = (const float*)d_in[4];
    const float* b_out = (const float*)d_in[5];
    const float* w_lin = (const float*)d_in[6];
    const float* b_lin = (const float*)d_in[7];
    float* out = (float*)d_out;

    const size_t S = (size_t)NB * HH * NS * DD;   // 2M elements
    unsigned short* qb   = (unsigned short*)d_ws;
    unsigned short* kb   = qb + S;
    unsigned short* vtb  = kb + S;
    unsigned short* ctxb = vtb + S;
    unsigned short* xb   = ctxb + S;
    unsigned short* wib  = xb + S;                // 768*256
    unsigned short* wcb  = wib + 768 * 256;       // 256*256
    unsigned int* adjbits = (unsigned int*)(wcb + 256 * 256);  // 32768 words
    float* bcomb = (float*)(adjbits + 32768);     // 256 floats

    dim3 blk(256);
    prep<<<dim3(944), blk, 0, stream>>>(x, w_in, w_out, b_out, w_lin, b_lin, adj,
                                        xb, wib, wcb, bcomb, adjbits);
    gemm_mfma<2, 128><<<dim3(768), blk, 0, stream>>>(xb, wib, b_in, nullptr, qb, kb, vtb, 768);
    attn_mfma<<<dim3(1024), blk, 0, stream>>>(qb, kb, vtb, adjbits, ctxb);
    gemm_mfma<1, 64><<<dim3(512), blk, 0, stream>>>(ctxb, wcb, bcomb, out, nullptr, nullptr, nullptr, 256);
}